// Round 9
// baseline (359.852 us; speedup 1.0000x reference)
//
#include <hip/hip_runtime.h>

// Problem constants: N=262144, D=32, Q=4, K=256
#define DIMS 32
#define NQ   4
#define KC   256
#define BETA 0.25f
#define FLTMAX 3.402823466e38f

typedef __attribute__((ext_vector_type(8))) short  short8;   // 8 bf16 (4 VGPRs)
typedef __attribute__((ext_vector_type(4))) float  floatx4;  // MFMA acc

// ROUND-17 (vs r7 anchor 119us; r8 LDS-staging REGRESSED 133us + small spill,
// rejected -- L2-direct loads already hidden, barriers/drains cost ~14us):
// Occupancy riddle: ~18% for EVERY variant regardless of LDS/VGPR_Count ->
// the hidden term is AGPRs (gfx950 unified file; acc regs not in VGPR_Count).
// r3's (256,4) crushing VGPR to 64 implies ~64 live AGPRs with NG=2. Real
// budget ~124+64=188 -> 2 waves/SIMD -> 58% stall with no saturated pipe.
// THIS ROUND: raise residency, numerics bit-identical to r7:
//  * NG=1: one 16-point group/wave (grid 4096): halves live state (r, rh/rl,
//    m1/m2, concurrent acc -> ~32 AGPR) at ~+20% issue/point.
//  * __launch_bounds__(256,3): compiler fits VGPR+AGPR <= ~170 -> >=3
//    waves/SIMD guaranteed.
// Failure modes pre-registered: FETCH/WRITE jump = spill -> revert bounds;
// flat dur+occupancy -> residency hypothesis wrong -> pivot to 32x32 MFMA.

__global__ void rvq_prep(const float* __restrict__ cb,      // [NQ, KC, DIMS]
                         short* __restrict__ ws_hi,         // [NQ*1024*8]
                         short* __restrict__ ws_lo,         // [NQ*1024*8]
                         float* __restrict__ ws_hn,         // [NQ*KC]
                         float* __restrict__ out_loss)
{
    const int q = blockIdx.x;
    const int t = threadIdx.x;
    if (q == 0 && t == 0) *out_loss = 0.f;
    const float* cbq = cb + (size_t)q * KC * DIMS;

    // exact fp32 half-norms, thread t <-> code t
    {
        const float4* c4 = (const float4*)(cbq + (size_t)t * DIMS);
        float s0 = 0.f, s1 = 0.f, s2 = 0.f, s3 = 0.f;
        #pragma unroll
        for (int j = 0; j < 8; ++j) {
            float4 f = c4[j];
            s0 = fmaf(f.x, f.x, s0); s1 = fmaf(f.y, f.y, s1);
            s2 = fmaf(f.z, f.z, s2); s3 = fmaf(f.w, f.w, s3);
        }
        ws_hn[(q << 8) + t] = 0.5f * ((s0 + s1) + (s2 + s3));
    }

    // negated trunc-split codebook; entry e = tt*64 + qo*16 + cl, 16 B each
    #pragma unroll
    for (int it = 0; it < 4; ++it) {
        int e = it * 256 + t;
        const float4* src = (const float4*)(cbq + (size_t)((e >> 6) * 16 + (e & 15)) * DIMS
                                            + ((e >> 4) & 3) * 8);
        float4 f0 = src[0], f1 = src[1];
        unsigned u[8];
        u[0]=__float_as_uint(f0.x)^0x80000000u; u[1]=__float_as_uint(f0.y)^0x80000000u;
        u[2]=__float_as_uint(f0.z)^0x80000000u; u[3]=__float_as_uint(f0.w)^0x80000000u;
        u[4]=__float_as_uint(f1.x)^0x80000000u; u[5]=__float_as_uint(f1.y)^0x80000000u;
        u[6]=__float_as_uint(f1.z)^0x80000000u; u[7]=__float_as_uint(f1.w)^0x80000000u;
        int4 hp, lp;
        int* hpi = (int*)&hp; int* lpi = (int*)&lp;
        #pragma unroll
        for (int p = 0; p < 4; ++p) {
            unsigned a = u[2*p], b = u[2*p+1];
            hpi[p] = (int)((b & 0xFFFF0000u) | (a >> 16));
            float ea = __uint_as_float(a) - __uint_as_float(a & 0xFFFF0000u);
            float eb = __uint_as_float(b) - __uint_as_float(b & 0xFFFF0000u);
            unsigned ua = __float_as_uint(ea), ub = __float_as_uint(eb);
            lpi[p] = (int)((ub & 0xFFFF0000u) | (ua >> 16));
        }
        *(int4*)(&ws_hi[(size_t)((q << 10) + e) << 3]) = hp;
        *(int4*)(&ws_lo[(size_t)((q << 10) + e) << 3]) = lp;
    }
}

__launch_bounds__(256, 3)
__global__ void rvq_kernel(const float* __restrict__ x,
                           const float* __restrict__ cb,      // [NQ, KC, DIMS] fp32 (gather/rescan)
                           const short* __restrict__ ws_hi,   // preconverted hi (L2-resident)
                           const short* __restrict__ ws_lo,   // preconverted lo (L2-resident)
                           const float* __restrict__ ws_hn,   // half-norms
                           float* __restrict__ out_xq,        // [N, DIMS]
                           float* __restrict__ out_loss,      // [1] pre-zeroed by prep
                           float* __restrict__ out_idx)       // [N, NQ] as float
{
    __shared__ float s_hn[NQ * KC];                  // 4 KB: 0.5*||c||^2, all stages
    __shared__ float s_ws[4];

    const int t  = threadIdx.x;
    const int l  = t & 63;
    const int w  = t >> 6;
    const int qo = l >> 4;       // dim-octet (0..3)
    const int cl = l & 15;       // point-in-group / code-in-tile

    const int base = blockIdx.x * 64 + w * 16;   // wave covers 16 points (NG=1)

    // ---- all-stage half-norms into LDS once ----
    #pragma unroll
    for (int i = 0; i < 4; ++i) s_hn[(i << 8) + t] = ws_hn[(i << 8) + t];

    // ---- residual: [8 dims], 8 VGPRs ----
    float r[8];
    {
        const float4* xp = (const float4*)(x + (size_t)(base + cl) * DIMS + qo * 8);
        float4 a = xp[0], c = xp[1];
        r[0]=a.x; r[1]=a.y; r[2]=a.z; r[3]=a.w;
        r[4]=c.x; r[5]=c.y; r[6]=c.z; r[7]=c.w;
    }

    __syncthreads();   // s_hn ready (the ONLY barrier until the loss epilogue)

    float la = 0.f;   // sum over own dims of ||r_new||^2, all stages

    for (int q = 0; q < NQ; ++q) {
        const float* cbq = cb + (size_t)q * KC * DIMS;
        const float* hnq = &s_hn[q << 8];
        const short8* gh  = (const short8*)(ws_hi + ((size_t)q << 13));  // 1024 entries
        const short8* gl8 = (const short8*)(ws_lo + ((size_t)q << 13));

        // ---- B-fragment: trunc-split bf16 of residual (unnegated) ----
        short8 rh, rl;
        {
            int4 hp, lp;
            int* hpi = (int*)&hp; int* lpi = (int*)&lp;
            #pragma unroll
            for (int p = 0; p < 4; ++p) {
                unsigned a = __float_as_uint(r[2*p]);
                unsigned b = __float_as_uint(r[2*p+1]);
                hpi[p] = (int)((b & 0xFFFF0000u) | (a >> 16));
                float ea = r[2*p]   - __uint_as_float(a & 0xFFFF0000u);
                float eb = r[2*p+1] - __uint_as_float(b & 0xFFFF0000u);
                unsigned ua = __float_as_uint(ea), ub = __float_as_uint(eb);
                lpi[p] = (int)((ub & 0xFFFF0000u) | (ua >> 16));
            }
            rh = *(short8*)&hp;
            rl = *(short8*)&lp;
        }

        // ---- ||r||^2 per point (consumed only by eps below) ----
        float rn;
        {
            float p0 = 0.f;
            #pragma unroll
            for (int j = 0; j < 8; ++j) p0 = fmaf(r[j], r[j], p0);
            p0 += __shfl_xor(p0, 16);
            p0 += __shfl_xor(p0, 32);
            rn = p0;
        }

        // ---- MFMA tile loop: acc init = hn ONLY (deferred hrn, r7-proven);
        //      L2-direct loads + 2-deep reg prefetch ----
        float m1[4], m2[4];
        #pragma unroll
        for (int i = 0; i < 4; ++i) { m1[i] = FLTMAX; m2[i] = FLTMAX; }

        short8 chA = gh[l],      clA = gl8[l];
        short8 chB = gh[64 + l], clB = gl8[64 + l];
        #pragma unroll
        for (int tt = 0; tt < 16; ++tt) {
            short8 chC = chA, clC = clA;   // dead on last 2 iters
            if (tt + 2 < 16) { chC = gh[((tt+2) << 6) + l]; clC = gl8[((tt+2) << 6) + l]; }
            const float4 hn4 = *(const float4*)(&hnq[(tt << 4) + (qo << 2)]);  // LDS broadcast
            floatx4 acc = {hn4.x, hn4.y, hn4.z, hn4.w};
            acc = __builtin_amdgcn_mfma_f32_16x16x32_bf16(chA, rh, acc, 0, 0, 0);
            acc = __builtin_amdgcn_mfma_f32_16x16x32_bf16(chA, rl, acc, 0, 0, 0);
            acc = __builtin_amdgcn_mfma_f32_16x16x32_bf16(clA, rh, acc, 0, 0, 0);
            #pragma unroll
            for (int i = 0; i < 4; ++i) {
                float pm = __uint_as_float((__float_as_uint(acc[i]) & 0xFFFFFF00u)
                                           | (unsigned)((tt << 2) | i));
                m2[i] = __builtin_amdgcn_fmed3f(pm, m1[i], m2[i]);
                m1[i] = fminf(pm, m1[i]);
            }
            chA = chB; clA = clB; chB = chC; clB = clC;
        }

        int bip; bool flg;
        {
            // resolve packed (tt<<2)|i -> full code tt*16 + qo*4 + i (order-preserving)
            #pragma unroll
            for (int i = 0; i < 4; ++i) {
                unsigned u = __float_as_uint(m1[i]);
                unsigned low = u & 0xFFu;
                unsigned full = ((low & 0xFCu) << 2) | ((unsigned)qo << 2) | (low & 3u);
                m1[i] = __uint_as_float((u & 0xFFFFFF00u) | full);
            }
            // merge 4 regs -> (M1, M2)
            float p1 = fminf(m1[0], m1[1]);
            float ph = fmaxf(m1[0], m1[1]);
            float p2 = fminf(fminf(m2[0], m2[1]), ph);
            float s1 = fminf(m1[2], m1[3]);
            float sh = fmaxf(m1[2], m1[3]);
            float s2 = fminf(fminf(m2[2], m2[3]), sh);
            float hh = fmaxf(p1, s1);
            float M1 = fminf(p1, s1);
            float M2 = fminf(fminf(p2, s2), hh);
            // merge across the 4 owner lanes (xor 16, 32) — lands where it's consumed
            #pragma unroll
            for (int off = 16; off <= 32; off <<= 1) {
                float o1 = __shfl_xor(M1, off);
                float o2 = __shfl_xor(M2, off);
                float h2 = fmaxf(M1, o1);
                M1 = fminf(M1, o1);
                M2 = fminf(fminf(M2, o2), h2);
            }
            bip = (int)(__float_as_uint(M1) & 0xFFu);
            float a1 = __uint_as_float(__float_as_uint(M1) & 0xFFFFFF00u);
            float a2 = __uint_as_float(__float_as_uint(M2) & 0xFFFFFF00u);
            // trunc-split bf16x3 error + packing quantization (packed-domain |a1|),
            // 4x margin (half-units). Gap a2-a1 is hrn-shift-invariant.
            float eps = fmaf(sqrtf(rn), 1.5e-3f, fmaf(fabsf(a1), 3e-5f, 1e-6f));
            flg = (a2 - a1) < eps;
        }

        // ---- rare: exact fp32 wave-cooperative rescan of ambiguous points ----
        {
            unsigned long long bm = __ballot((l < 16) && flg);
            while (bm) {
                int p = __ffsll(bm) - 1;
                bm &= bm - 1;
                float rp[32];
                #pragma unroll
                for (int qq = 0; qq < 4; ++qq)
                    #pragma unroll
                    for (int j = 0; j < 8; ++j)
                        rp[qq*8 + j] = __shfl(r[j], qq*16 + p);
                float bests = FLTMAX; int bestk = 0;
                #pragma unroll
                for (int c = 0; c < 4; ++c) {
                    int k = (c << 6) + l;
                    const float4* ck = (const float4*)(cbq + (size_t)k * DIMS);
                    float a0=0.f,a1=0.f,a2=0.f,a3=0.f;
                    #pragma unroll
                    for (int j = 0; j < 8; ++j) {
                        float4 f = ck[j];
                        a0 = fmaf(rp[4*j+0], f.x, a0);
                        a1 = fmaf(rp[4*j+1], f.y, a1);
                        a2 = fmaf(rp[4*j+2], f.z, a2);
                        a3 = fmaf(rp[4*j+3], f.w, a3);
                    }
                    float sc = fmaf(-2.f, (a0+a1)+(a2+a3), 2.f * hnq[k]);
                    bool lt = sc < bests;
                    bests = lt ? sc : bests;  bestk = lt ? k : bestk;
                }
                #pragma unroll
                for (int off = 1; off < 64; off <<= 1) {
                    float so = __shfl_xor(bests, off);
                    int   ko = __shfl_xor(bestk, off);
                    bool take = (so < bests) || (so == bests && ko < bestk);
                    bests = take ? so : bests;
                    bestk = take ? ko : bestk;
                }
                if (cl == p) bip = bestk;
            }
        }

        // ---- gather chosen code (exact fp32), update residual, loss, indices ----
        {
            const float4* cq = (const float4*)(cbq + (size_t)bip * DIMS + qo * 8);
            float4 c0 = cq[0], c1 = cq[1];
            r[0]-=c0.x; r[1]-=c0.y; r[2]-=c0.z; r[3]-=c0.w;
            r[4]-=c1.x; r[5]-=c1.y; r[6]-=c1.z; r[7]-=c1.w;
            #pragma unroll
            for (int j = 0; j < 8; ++j) la = fmaf(r[j], r[j], la);
            if (l < 16)
                out_idx[(size_t)(base + l) * NQ + q] = (float)bip;
        }
    }

    // ---- epilogue: x_q = x - r_final ----
    {
        size_t o = (size_t)(base + cl) * DIMS + qo * 8;
        const float4* xp = (const float4*)(x + o);
        float4 a = xp[0], c = xp[1];
        float4* op = (float4*)(out_xq + o);
        op[0] = make_float4(a.x - r[0], a.y - r[1], a.z - r[2], a.w - r[3]);
        op[1] = make_float4(c.x - r[4], c.y - r[5], c.z - r[6], c.w - r[7]);
    }

    // ---- loss: wave -> block -> one atomicAdd ----
    float v = la;
    #pragma unroll
    for (int off = 1; off < 64; off <<= 1)
        v += __shfl_xor(v, off);
    if (l == 0) s_ws[w] = v;
    __syncthreads();
    if (t == 0) {
        const float scale = (1.0f + BETA) / ((float)NQ * 262144.0f * (float)DIMS);
        atomicAdd(out_loss, (s_ws[0] + s_ws[1] + s_ws[2] + s_ws[3]) * scale);
    }
}

extern "C" void kernel_launch(void* const* d_in, const int* in_sizes, int n_in,
                              void* d_out, int out_size, void* d_ws, size_t ws_size,
                              hipStream_t stream) {
    const float* x  = (const float*)d_in[0];   // [N, 32]
    const float* cb = (const float*)d_in[1];   // [4, 256, 32]
    float* out = (float*)d_out;

    const int N = in_sizes[0] / DIMS;          // 262144
    float* out_xq   = out;
    float* out_loss = out + (size_t)N * DIMS;
    float* out_idx  = out + (size_t)N * DIMS + 1;

    // workspace layout: hi [4*1024*16B] | lo [4*1024*16B] | hn [4*256*4B] = 132 KB
    short* ws_hi = (short*)d_ws;
    short* ws_lo = (short*)((char*)d_ws + 65536);
    float* ws_hn = (float*)((char*)d_ws + 131072);

    rvq_prep<<<dim3(NQ), dim3(KC), 0, stream>>>(cb, ws_hi, ws_lo, ws_hn, out_loss);
    rvq_kernel<<<dim3(N / 64), dim3(256), 0, stream>>>(x, cb, ws_hi, ws_lo, ws_hn,
                                                       out_xq, out_loss, out_idx);
}

// Round 10
// 165.359 us; speedup vs baseline: 2.1762x; 2.1762x over previous
//
#include <hip/hip_runtime.h>

// Problem constants: N=262144, D=32, Q=4, K=256
#define DIMS 32
#define NQ   4
#define KC   256
#define BETA 0.25f
#define FLTMAX 3.402823466e38f

typedef __attribute__((ext_vector_type(8))) short  short8;   // 8 bf16 (4 VGPRs)
typedef __attribute__((ext_vector_type(4))) float  floatx4;  // MFMA acc

// ROUND-18 (vs r7 anchor 119us; r8 LDS-staging 133us REJECTED; r9 NG=1+
// bounds(256,3) 296us REJECTED -- spill storm: FETCH 177MB/WRITE 433MB at
// VGPR 84 proves live state ~190 regs/wave -> 2 waves/SIMD is the residency
// ceiling; stop buying TLP, attack the per-wave work).
// VALU books don't balance: ~10.3k VALU/wave measured vs ~2.9k static for the
// structured code. Prime suspect: the "rare" rescan isn't rare. At
// eps ~ 1e-2 (1.5e-3*sqrt(rn) at rn~32) vs top-2 gaps ~0.1-0.3 for 256 random
// codes, ambiguity ~5%/point -> P(>=1 rescan per 16-pt group) ~60%, each a
// ~200-op serial chain x8 groups x4 stages.
// Re-derived worst-case split error (Cauchy-Schwarz, two-level trunc-bf16,
// dropped lo*lo): e_split <= 2^-16*||c||*||r|| ~= 1.3e-4*sqrt(rn) half-units.
// Old coefficient 1.5e-3 was 12x worst-case (mislabeled "4x margin").
// THIS ROUND (single change, clean attribution): eps coefficients
// 1.5e-3 -> 4e-4 (3x worst-case) and 3e-5 -> 4e-5 (1.3 packing quanta).
// Everything else bit-identical to r7.
// Predictions: theory(a) rescan-cost: dur -> 95-105us. Flat: rescans
// exonerated -> pivot to 32x32x16 MFMA restructure. absmax fail -> revert
// coefficient (pre-registered).

__global__ void rvq_prep(const float* __restrict__ cb,      // [NQ, KC, DIMS]
                         short* __restrict__ ws_hi,         // [NQ*1024*8]
                         short* __restrict__ ws_lo,         // [NQ*1024*8]
                         float* __restrict__ ws_hn,         // [NQ*KC]
                         float* __restrict__ out_loss)
{
    const int q = blockIdx.x;
    const int t = threadIdx.x;
    if (q == 0 && t == 0) *out_loss = 0.f;
    const float* cbq = cb + (size_t)q * KC * DIMS;

    // exact fp32 half-norms, thread t <-> code t
    {
        const float4* c4 = (const float4*)(cbq + (size_t)t * DIMS);
        float s0 = 0.f, s1 = 0.f, s2 = 0.f, s3 = 0.f;
        #pragma unroll
        for (int j = 0; j < 8; ++j) {
            float4 f = c4[j];
            s0 = fmaf(f.x, f.x, s0); s1 = fmaf(f.y, f.y, s1);
            s2 = fmaf(f.z, f.z, s2); s3 = fmaf(f.w, f.w, s3);
        }
        ws_hn[(q << 8) + t] = 0.5f * ((s0 + s1) + (s2 + s3));
    }

    // negated trunc-split codebook; entry e = tt*64 + qo*16 + cl, 16 B each
    #pragma unroll
    for (int it = 0; it < 4; ++it) {
        int e = it * 256 + t;
        const float4* src = (const float4*)(cbq + (size_t)((e >> 6) * 16 + (e & 15)) * DIMS
                                            + ((e >> 4) & 3) * 8);
        float4 f0 = src[0], f1 = src[1];
        unsigned u[8];
        u[0]=__float_as_uint(f0.x)^0x80000000u; u[1]=__float_as_uint(f0.y)^0x80000000u;
        u[2]=__float_as_uint(f0.z)^0x80000000u; u[3]=__float_as_uint(f0.w)^0x80000000u;
        u[4]=__float_as_uint(f1.x)^0x80000000u; u[5]=__float_as_uint(f1.y)^0x80000000u;
        u[6]=__float_as_uint(f1.z)^0x80000000u; u[7]=__float_as_uint(f1.w)^0x80000000u;
        int4 hp, lp;
        int* hpi = (int*)&hp; int* lpi = (int*)&lp;
        #pragma unroll
        for (int p = 0; p < 4; ++p) {
            unsigned a = u[2*p], b = u[2*p+1];
            hpi[p] = (int)((b & 0xFFFF0000u) | (a >> 16));
            float ea = __uint_as_float(a) - __uint_as_float(a & 0xFFFF0000u);
            float eb = __uint_as_float(b) - __uint_as_float(b & 0xFFFF0000u);
            unsigned ua = __float_as_uint(ea), ub = __float_as_uint(eb);
            lpi[p] = (int)((ub & 0xFFFF0000u) | (ua >> 16));
        }
        *(int4*)(&ws_hi[(size_t)((q << 10) + e) << 3]) = hp;
        *(int4*)(&ws_lo[(size_t)((q << 10) + e) << 3]) = lp;
    }
}

__launch_bounds__(256, 2)
__global__ void rvq_kernel(const float* __restrict__ x,
                           const float* __restrict__ cb,      // [NQ, KC, DIMS] fp32 (gather/rescan)
                           const short* __restrict__ ws_hi,   // preconverted hi (L2-resident)
                           const short* __restrict__ ws_lo,   // preconverted lo (L2-resident)
                           const float* __restrict__ ws_hn,   // half-norms
                           float* __restrict__ out_xq,        // [N, DIMS]
                           float* __restrict__ out_loss,      // [1] pre-zeroed by prep
                           float* __restrict__ out_idx)       // [N, NQ] as float
{
    __shared__ float s_hn[NQ * KC];                  // 4 KB: 0.5*||c||^2, all stages
    __shared__ float s_ws[4];

    const int t  = threadIdx.x;
    const int l  = t & 63;
    const int w  = t >> 6;
    const int qo = l >> 4;       // dim-octet (0..3)
    const int cl = l & 15;       // point-in-group / code-in-tile

    const int base = blockIdx.x * 128 + w * 32;   // wave covers 32 points (2 groups of 16)

    // ---- all-stage half-norms into LDS once ----
    #pragma unroll
    for (int i = 0; i < 4; ++i) s_hn[(i << 8) + t] = ws_hn[(i << 8) + t];

    // ---- residuals: [group][8 dims], 16 VGPRs ----
    float r[2][8];
    #pragma unroll
    for (int g = 0; g < 2; ++g) {
        const float4* xp = (const float4*)(x + (size_t)(base + g*16 + cl) * DIMS + qo * 8);
        float4 a = xp[0], c = xp[1];
        r[g][0]=a.x; r[g][1]=a.y; r[g][2]=a.z; r[g][3]=a.w;
        r[g][4]=c.x; r[g][5]=c.y; r[g][6]=c.z; r[g][7]=c.w;
    }

    __syncthreads();   // s_hn ready (the ONLY barrier until the loss epilogue)

    float la = 0.f;   // sum over own dims of ||r_new||^2, all stages

    for (int q = 0; q < NQ; ++q) {
        const float* cbq = cb + (size_t)q * KC * DIMS;
        const float* hnq = &s_hn[q << 8];
        const short8* gh  = (const short8*)(ws_hi + ((size_t)q << 13));  // 1024 entries
        const short8* gl8 = (const short8*)(ws_lo + ((size_t)q << 13));

        // ---- B-fragments: trunc-split bf16 of residual (unnegated) ----
        short8 rh[2], rl[2];
        #pragma unroll
        for (int g = 0; g < 2; ++g) {
            int4 hp, lp;
            int* hpi = (int*)&hp; int* lpi = (int*)&lp;
            #pragma unroll
            for (int p = 0; p < 4; ++p) {
                unsigned a = __float_as_uint(r[g][2*p]);
                unsigned b = __float_as_uint(r[g][2*p+1]);
                hpi[p] = (int)((b & 0xFFFF0000u) | (a >> 16));
                float ea = r[g][2*p]   - __uint_as_float(a & 0xFFFF0000u);
                float eb = r[g][2*p+1] - __uint_as_float(b & 0xFFFF0000u);
                unsigned ua = __float_as_uint(ea), ub = __float_as_uint(eb);
                lpi[p] = (int)((ub & 0xFFFF0000u) | (ua >> 16));
            }
            rh[g] = *(short8*)&hp;
            rl[g] = *(short8*)&lp;
        }

        // ---- MFMA tile loop: acc init = hn ONLY (hrn deferred, shift-invariant);
        //      2-deep register prefetch pipeline over 16 tiles ----
        float m1[2][4], m2[2][4];
        #pragma unroll
        for (int g = 0; g < 2; ++g)
            #pragma unroll
            for (int i = 0; i < 4; ++i) { m1[g][i] = FLTMAX; m2[g][i] = FLTMAX; }

        short8 chA = gh[l],      clA = gl8[l];
        short8 chB = gh[64 + l], clB = gl8[64 + l];
        #pragma unroll
        for (int tt = 0; tt < 16; ++tt) {
            short8 chC = chA, clC = clA;   // dead on last 2 iters
            if (tt + 2 < 16) { chC = gh[((tt+2) << 6) + l]; clC = gl8[((tt+2) << 6) + l]; }
            const float4 hn4 = *(const float4*)(&hnq[(tt << 4) + (qo << 2)]);  // LDS broadcast
            #pragma unroll
            for (int g = 0; g < 2; ++g) {
                floatx4 acc = {hn4.x, hn4.y, hn4.z, hn4.w};
                acc = __builtin_amdgcn_mfma_f32_16x16x32_bf16(chA, rh[g], acc, 0, 0, 0);
                acc = __builtin_amdgcn_mfma_f32_16x16x32_bf16(chA, rl[g], acc, 0, 0, 0);
                acc = __builtin_amdgcn_mfma_f32_16x16x32_bf16(clA, rh[g], acc, 0, 0, 0);
                #pragma unroll
                for (int i = 0; i < 4; ++i) {
                    float pm = __uint_as_float((__float_as_uint(acc[i]) & 0xFFFFFF00u)
                                               | (unsigned)((tt << 2) | i));
                    m2[g][i] = __builtin_amdgcn_fmed3f(pm, m1[g][i], m2[g][i]);
                    m1[g][i] = fminf(pm, m1[g][i]);
                }
            }
            chA = chB; clA = clB; chB = chC; clB = clC;
        }

        // ---- ||r||^2 per point (consumed only by eps below; off critical path) ----
        float rn[2];
        #pragma unroll
        for (int g = 0; g < 2; ++g) {
            float p0 = 0.f;
            #pragma unroll
            for (int j = 0; j < 8; ++j) p0 = fmaf(r[g][j], r[g][j], p0);
            p0 += __shfl_xor(p0, 16);
            p0 += __shfl_xor(p0, 32);
            rn[g] = p0;
        }

        int bip[2]; bool flg[2];
        #pragma unroll
        for (int g = 0; g < 2; ++g) {
            // resolve packed (tt<<2)|i -> full code tt*16 + qo*4 + i (order-preserving)
            #pragma unroll
            for (int i = 0; i < 4; ++i) {
                unsigned u = __float_as_uint(m1[g][i]);
                unsigned low = u & 0xFFu;
                unsigned full = ((low & 0xFCu) << 2) | ((unsigned)qo << 2) | (low & 3u);
                m1[g][i] = __uint_as_float((u & 0xFFFFFF00u) | full);
            }
            // merge 4 regs -> (M1, M2)
            float p1 = fminf(m1[g][0], m1[g][1]);
            float ph = fmaxf(m1[g][0], m1[g][1]);
            float p2 = fminf(fminf(m2[g][0], m2[g][1]), ph);
            float s1 = fminf(m1[g][2], m1[g][3]);
            float sh = fmaxf(m1[g][2], m1[g][3]);
            float s2 = fminf(fminf(m2[g][2], m2[g][3]), sh);
            float hh = fmaxf(p1, s1);
            float M1 = fminf(p1, s1);
            float M2 = fminf(fminf(p2, s2), hh);
            // merge across the 4 owner lanes (xor 16, 32) — lands where it's consumed
            #pragma unroll
            for (int off = 16; off <= 32; off <<= 1) {
                float o1 = __shfl_xor(M1, off);
                float o2 = __shfl_xor(M2, off);
                float h2 = fmaxf(M1, o1);
                M1 = fminf(M1, o1);
                M2 = fminf(fminf(M2, o2), h2);
            }
            bip[g] = (int)(__float_as_uint(M1) & 0xFFu);
            float a1 = __uint_as_float(__float_as_uint(M1) & 0xFFFFFF00u);
            float a2 = __uint_as_float(__float_as_uint(M2) & 0xFFFFFF00u);
            // TIGHTENED bound (r18): worst-case trunc-split error (Cauchy-Schwarz)
            // e_split <= 2^-16*||c||*||r|| ~ 1.3e-4*sqrt(rn) half-units -> 3x margin
            // at 4e-4; packing quantization ~1.3 quanta at 4e-5*|a1|.
            float eps = fmaf(sqrtf(rn[g]), 4e-4f, fmaf(fabsf(a1), 4e-5f, 1e-6f));
            flg[g] = (a2 - a1) < eps;
        }

        // ---- rare: exact fp32 wave-cooperative rescan of ambiguous points ----
        #pragma unroll
        for (int g = 0; g < 2; ++g) {
            unsigned long long bm = __ballot((l < 16) && flg[g]);
            while (bm) {
                int p = __ffsll(bm) - 1;
                bm &= bm - 1;
                float rp[32];
                #pragma unroll
                for (int qq = 0; qq < 4; ++qq)
                    #pragma unroll
                    for (int j = 0; j < 8; ++j)
                        rp[qq*8 + j] = __shfl(r[g][j], qq*16 + p);
                float bests = FLTMAX; int bestk = 0;
                #pragma unroll
                for (int c = 0; c < 4; ++c) {
                    int k = (c << 6) + l;
                    const float4* ck = (const float4*)(cbq + (size_t)k * DIMS);
                    float a0=0.f,a1=0.f,a2=0.f,a3=0.f;
                    #pragma unroll
                    for (int j = 0; j < 8; ++j) {
                        float4 f = ck[j];
                        a0 = fmaf(rp[4*j+0], f.x, a0);
                        a1 = fmaf(rp[4*j+1], f.y, a1);
                        a2 = fmaf(rp[4*j+2], f.z, a2);
                        a3 = fmaf(rp[4*j+3], f.w, a3);
                    }
                    float sc = fmaf(-2.f, (a0+a1)+(a2+a3), 2.f * hnq[k]);
                    bool lt = sc < bests;
                    bests = lt ? sc : bests;  bestk = lt ? k : bestk;
                }
                #pragma unroll
                for (int off = 1; off < 64; off <<= 1) {
                    float so = __shfl_xor(bests, off);
                    int   ko = __shfl_xor(bestk, off);
                    bool take = (so < bests) || (so == bests && ko < bestk);
                    bests = take ? so : bests;
                    bestk = take ? ko : bestk;
                }
                if (cl == p) bip[g] = bestk;
            }
        }

        // ---- gather chosen codes (exact fp32), update residual, loss, indices ----
        #pragma unroll
        for (int g = 0; g < 2; ++g) {
            const float4* cq = (const float4*)(cbq + (size_t)bip[g] * DIMS + qo * 8);
            float4 c0 = cq[0], c1 = cq[1];
            r[g][0]-=c0.x; r[g][1]-=c0.y; r[g][2]-=c0.z; r[g][3]-=c0.w;
            r[g][4]-=c1.x; r[g][5]-=c1.y; r[g][6]-=c1.z; r[g][7]-=c1.w;
            #pragma unroll
            for (int j = 0; j < 8; ++j) la = fmaf(r[g][j], r[g][j], la);
            if (l < 16)
                out_idx[(size_t)(base + g*16 + l) * NQ + q] = (float)bip[g];
        }
    }

    // ---- epilogue: x_q = x - r_final ----
    #pragma unroll
    for (int g = 0; g < 2; ++g) {
        size_t o = (size_t)(base + g*16 + cl) * DIMS + qo * 8;
        const float4* xp = (const float4*)(x + o);
        float4 a = xp[0], c = xp[1];
        float4* op = (float4*)(out_xq + o);
        op[0] = make_float4(a.x - r[g][0], a.y - r[g][1], a.z - r[g][2], a.w - r[g][3]);
        op[1] = make_float4(c.x - r[g][4], c.y - r[g][5], c.z - r[g][6], c.w - r[g][7]);
    }

    // ---- loss: wave -> block -> one atomicAdd ----
    float v = la;
    #pragma unroll
    for (int off = 1; off < 64; off <<= 1)
        v += __shfl_xor(v, off);
    if (l == 0) s_ws[w] = v;
    __syncthreads();
    if (t == 0) {
        const float scale = (1.0f + BETA) / ((float)NQ * 262144.0f * (float)DIMS);
        atomicAdd(out_loss, (s_ws[0] + s_ws[1] + s_ws[2] + s_ws[3]) * scale);
    }
}

extern "C" void kernel_launch(void* const* d_in, const int* in_sizes, int n_in,
                              void* d_out, int out_size, void* d_ws, size_t ws_size,
                              hipStream_t stream) {
    const float* x  = (const float*)d_in[0];   // [N, 32]
    const float* cb = (const float*)d_in[1];   // [4, 256, 32]
    float* out = (float*)d_out;

    const int N = in_sizes[0] / DIMS;          // 262144
    float* out_xq   = out;
    float* out_loss = out + (size_t)N * DIMS;
    float* out_idx  = out + (size_t)N * DIMS + 1;

    // workspace layout: hi [4*1024*16B] | lo [4*1024*16B] | hn [4*256*4B] = 132 KB
    short* ws_hi = (short*)d_ws;
    short* ws_lo = (short*)((char*)d_ws + 65536);
    float* ws_hn = (float*)((char*)d_ws + 131072);

    rvq_prep<<<dim3(NQ), dim3(KC), 0, stream>>>(cb, ws_hi, ws_lo, ws_hn, out_loss);
    rvq_kernel<<<dim3(N / 128), dim3(256), 0, stream>>>(x, cb, ws_hi, ws_lo, ws_hn,
                                                        out_xq, out_loss, out_idx);
}

// Round 11
// 164.412 us; speedup vs baseline: 2.1887x; 1.0058x over previous
//
#include <hip/hip_runtime.h>

// Problem constants: N=262144, D=32, Q=4, K=256
#define DIMS 32
#define NQ   4
#define KC   256
#define BETA 0.25f
#define FLTMAX 3.402823466e38f

typedef __attribute__((ext_vector_type(8))) short  short8;   // 8 bf16 (4 VGPRs)
typedef __attribute__((ext_vector_type(4))) float  floatx4;  // MFMA acc

// ROUND-19 (vs r10 anchor 102us, absmax 0.015625):
// r10 confirmed rescan theory (119->102 via sound eps tightening). ERRATum:
// careful re-derivation of the trunc-split bound gives e <= 3*2^-16*||c||*||r||
// ~= 2.6e-4*sqrt(rn) -> current 4e-4 is ~1.5x worst case. DO NOT tighten more.
// Books now: ~7.5k VALU insts/wave -> 50us at full issue; 102us @ 49% VALUBusy
// -> waves ~88% stalled on their OWN serial chains. Occupancy metric reads
// ~0.4x theoretical residency consistently (r9: 30% @ VGPR84, r10: 19% @124)
// -> actual residency ~4 waves/SIMD; r8 proved in-loop loads already hidden.
// Biggest exposed serial latency: post-loop cross-lane merge = 2 DEPENDENT
// shfl_xor rounds (~100-120cyc each, LDS pipe), with rn's 2 serial shuffles
// adjacent.
// THIS ROUND (register-neutral, numerics bit-identical):
//  * Single-round merge: 6 INDEPENDENT __shfl pulls (l^16/l^32/l^48 for M1,M2),
//    latencies overlap; 12-op min/secondmin tree replaces 2 serial rounds.
//  * rn computed BEFORE the tile loop (+2 regs): its shuffle latency hides
//    under the loop instead of the merge path.
//  * Both groups' ballots computed upfront before the rescan loops.
// Pre-registered: flat result => cross-lane latency exonerated => wall is the
// tile loop => 32x32x16 restructure or near-floor. FETCH/WRITE jump => spill
// => revert rn hoist.

__global__ void rvq_prep(const float* __restrict__ cb,      // [NQ, KC, DIMS]
                         short* __restrict__ ws_hi,         // [NQ*1024*8]
                         short* __restrict__ ws_lo,         // [NQ*1024*8]
                         float* __restrict__ ws_hn,         // [NQ*KC]
                         float* __restrict__ out_loss)
{
    const int q = blockIdx.x;
    const int t = threadIdx.x;
    if (q == 0 && t == 0) *out_loss = 0.f;
    const float* cbq = cb + (size_t)q * KC * DIMS;

    // exact fp32 half-norms, thread t <-> code t
    {
        const float4* c4 = (const float4*)(cbq + (size_t)t * DIMS);
        float s0 = 0.f, s1 = 0.f, s2 = 0.f, s3 = 0.f;
        #pragma unroll
        for (int j = 0; j < 8; ++j) {
            float4 f = c4[j];
            s0 = fmaf(f.x, f.x, s0); s1 = fmaf(f.y, f.y, s1);
            s2 = fmaf(f.z, f.z, s2); s3 = fmaf(f.w, f.w, s3);
        }
        ws_hn[(q << 8) + t] = 0.5f * ((s0 + s1) + (s2 + s3));
    }

    // negated trunc-split codebook; entry e = tt*64 + qo*16 + cl, 16 B each
    #pragma unroll
    for (int it = 0; it < 4; ++it) {
        int e = it * 256 + t;
        const float4* src = (const float4*)(cbq + (size_t)((e >> 6) * 16 + (e & 15)) * DIMS
                                            + ((e >> 4) & 3) * 8);
        float4 f0 = src[0], f1 = src[1];
        unsigned u[8];
        u[0]=__float_as_uint(f0.x)^0x80000000u; u[1]=__float_as_uint(f0.y)^0x80000000u;
        u[2]=__float_as_uint(f0.z)^0x80000000u; u[3]=__float_as_uint(f0.w)^0x80000000u;
        u[4]=__float_as_uint(f1.x)^0x80000000u; u[5]=__float_as_uint(f1.y)^0x80000000u;
        u[6]=__float_as_uint(f1.z)^0x80000000u; u[7]=__float_as_uint(f1.w)^0x80000000u;
        int4 hp, lp;
        int* hpi = (int*)&hp; int* lpi = (int*)&lp;
        #pragma unroll
        for (int p = 0; p < 4; ++p) {
            unsigned a = u[2*p], b = u[2*p+1];
            hpi[p] = (int)((b & 0xFFFF0000u) | (a >> 16));
            float ea = __uint_as_float(a) - __uint_as_float(a & 0xFFFF0000u);
            float eb = __uint_as_float(b) - __uint_as_float(b & 0xFFFF0000u);
            unsigned ua = __float_as_uint(ea), ub = __float_as_uint(eb);
            lpi[p] = (int)((ub & 0xFFFF0000u) | (ua >> 16));
        }
        *(int4*)(&ws_hi[(size_t)((q << 10) + e) << 3]) = hp;
        *(int4*)(&ws_lo[(size_t)((q << 10) + e) << 3]) = lp;
    }
}

__launch_bounds__(256, 2)
__global__ void rvq_kernel(const float* __restrict__ x,
                           const float* __restrict__ cb,      // [NQ, KC, DIMS] fp32 (gather/rescan)
                           const short* __restrict__ ws_hi,   // preconverted hi (L2-resident)
                           const short* __restrict__ ws_lo,   // preconverted lo (L2-resident)
                           const float* __restrict__ ws_hn,   // half-norms
                           float* __restrict__ out_xq,        // [N, DIMS]
                           float* __restrict__ out_loss,      // [1] pre-zeroed by prep
                           float* __restrict__ out_idx)       // [N, NQ] as float
{
    __shared__ float s_hn[NQ * KC];                  // 4 KB: 0.5*||c||^2, all stages
    __shared__ float s_ws[4];

    const int t  = threadIdx.x;
    const int l  = t & 63;
    const int w  = t >> 6;
    const int qo = l >> 4;       // dim-octet (0..3)
    const int cl = l & 15;       // point-in-group / code-in-tile

    const int base = blockIdx.x * 128 + w * 32;   // wave covers 32 points (2 groups of 16)

    // ---- all-stage half-norms into LDS once ----
    #pragma unroll
    for (int i = 0; i < 4; ++i) s_hn[(i << 8) + t] = ws_hn[(i << 8) + t];

    // ---- residuals: [group][8 dims], 16 VGPRs ----
    float r[2][8];
    #pragma unroll
    for (int g = 0; g < 2; ++g) {
        const float4* xp = (const float4*)(x + (size_t)(base + g*16 + cl) * DIMS + qo * 8);
        float4 a = xp[0], c = xp[1];
        r[g][0]=a.x; r[g][1]=a.y; r[g][2]=a.z; r[g][3]=a.w;
        r[g][4]=c.x; r[g][5]=c.y; r[g][6]=c.z; r[g][7]=c.w;
    }

    __syncthreads();   // s_hn ready (the ONLY barrier until the loss epilogue)

    float la = 0.f;   // sum over own dims of ||r_new||^2, all stages

    for (int q = 0; q < NQ; ++q) {
        const float* cbq = cb + (size_t)q * KC * DIMS;
        const float* hnq = &s_hn[q << 8];
        const short8* gh  = (const short8*)(ws_hi + ((size_t)q << 13));  // 1024 entries
        const short8* gl8 = (const short8*)(ws_lo + ((size_t)q << 13));

        // ---- B-fragments: trunc-split bf16 of residual (unnegated) ----
        short8 rh[2], rl[2];
        #pragma unroll
        for (int g = 0; g < 2; ++g) {
            int4 hp, lp;
            int* hpi = (int*)&hp; int* lpi = (int*)&lp;
            #pragma unroll
            for (int p = 0; p < 4; ++p) {
                unsigned a = __float_as_uint(r[g][2*p]);
                unsigned b = __float_as_uint(r[g][2*p+1]);
                hpi[p] = (int)((b & 0xFFFF0000u) | (a >> 16));
                float ea = r[g][2*p]   - __uint_as_float(a & 0xFFFF0000u);
                float eb = r[g][2*p+1] - __uint_as_float(b & 0xFFFF0000u);
                unsigned ua = __float_as_uint(ea), ub = __float_as_uint(eb);
                lpi[p] = (int)((ub & 0xFFFF0000u) | (ua >> 16));
            }
            rh[g] = *(short8*)&hp;
            rl[g] = *(short8*)&lp;
        }

        // ---- ||r||^2 per point: issued BEFORE the tile loop so its two serial
        //      shuffle latencies hide under the loop (consumed only by eps) ----
        float rn[2];
        #pragma unroll
        for (int g = 0; g < 2; ++g) {
            float p0 = 0.f;
            #pragma unroll
            for (int j = 0; j < 8; ++j) p0 = fmaf(r[g][j], r[g][j], p0);
            p0 += __shfl_xor(p0, 16);
            p0 += __shfl_xor(p0, 32);
            rn[g] = p0;
        }

        // ---- MFMA tile loop: acc init = hn ONLY (hrn deferred, shift-invariant);
        //      2-deep register prefetch pipeline over 16 tiles ----
        float m1[2][4], m2[2][4];
        #pragma unroll
        for (int g = 0; g < 2; ++g)
            #pragma unroll
            for (int i = 0; i < 4; ++i) { m1[g][i] = FLTMAX; m2[g][i] = FLTMAX; }

        short8 chA = gh[l],      clA = gl8[l];
        short8 chB = gh[64 + l], clB = gl8[64 + l];
        #pragma unroll
        for (int tt = 0; tt < 16; ++tt) {
            short8 chC = chA, clC = clA;   // dead on last 2 iters
            if (tt + 2 < 16) { chC = gh[((tt+2) << 6) + l]; clC = gl8[((tt+2) << 6) + l]; }
            const float4 hn4 = *(const float4*)(&hnq[(tt << 4) + (qo << 2)]);  // LDS broadcast
            #pragma unroll
            for (int g = 0; g < 2; ++g) {
                floatx4 acc = {hn4.x, hn4.y, hn4.z, hn4.w};
                acc = __builtin_amdgcn_mfma_f32_16x16x32_bf16(chA, rh[g], acc, 0, 0, 0);
                acc = __builtin_amdgcn_mfma_f32_16x16x32_bf16(chA, rl[g], acc, 0, 0, 0);
                acc = __builtin_amdgcn_mfma_f32_16x16x32_bf16(clA, rh[g], acc, 0, 0, 0);
                #pragma unroll
                for (int i = 0; i < 4; ++i) {
                    float pm = __uint_as_float((__float_as_uint(acc[i]) & 0xFFFFFF00u)
                                               | (unsigned)((tt << 2) | i));
                    m2[g][i] = __builtin_amdgcn_fmed3f(pm, m1[g][i], m2[g][i]);
                    m1[g][i] = fminf(pm, m1[g][i]);
                }
            }
            chA = chB; clA = clB; chB = chC; clB = clC;
        }

        int bip[2]; bool flg[2];
        #pragma unroll
        for (int g = 0; g < 2; ++g) {
            // resolve packed (tt<<2)|i -> full code tt*16 + qo*4 + i (order-preserving)
            #pragma unroll
            for (int i = 0; i < 4; ++i) {
                unsigned u = __float_as_uint(m1[g][i]);
                unsigned low = u & 0xFFu;
                unsigned full = ((low & 0xFCu) << 2) | ((unsigned)qo << 2) | (low & 3u);
                m1[g][i] = __uint_as_float((u & 0xFFFFFF00u) | full);
            }
            // merge 4 regs -> (M1, M2)
            float p1 = fminf(m1[g][0], m1[g][1]);
            float ph = fmaxf(m1[g][0], m1[g][1]);
            float p2 = fminf(fminf(m2[g][0], m2[g][1]), ph);
            float s1 = fminf(m1[g][2], m1[g][3]);
            float sh = fmaxf(m1[g][2], m1[g][3]);
            float s2 = fminf(fminf(m2[g][2], m2[g][3]), sh);
            float hh = fmaxf(p1, s1);
            float M1 = fminf(p1, s1);
            float M2 = fminf(fminf(p2, s2), hh);
            // SINGLE-ROUND cross-lane merge over owner lanes {l^16, l^32, l^48}:
            // 6 independent shuffles (latencies overlap) + min/secondmin tree.
            float a1v = __shfl(M1, l ^ 16);
            float b1v = __shfl(M1, l ^ 32);
            float c1v = __shfl(M1, l ^ 48);
            float a2v = __shfl(M2, l ^ 16);
            float b2v = __shfl(M2, l ^ 32);
            float c2v = __shfl(M2, l ^ 48);
            float lo1 = fminf(M1, a1v), hi1 = fmaxf(M1, a1v);
            float lo2 = fminf(b1v, c1v), hi2 = fmaxf(b1v, c1v);
            float M1n = fminf(lo1, lo2);
            float sm  = fminf(fmaxf(lo1, lo2), fminf(hi1, hi2));   // 2nd-min of 4 M1s
            float M2n = fminf(fminf(fminf(M2, a2v), fminf(b2v, c2v)), sm);
            bip[g] = (int)(__float_as_uint(M1n) & 0xFFu);
            float a1 = __uint_as_float(__float_as_uint(M1n) & 0xFFFFFF00u);
            float a2 = __uint_as_float(__float_as_uint(M2n) & 0xFFFFFF00u);
            // eps: 4e-4 ~ 1.5x the Cauchy-Schwarz worst-case split error (see
            // header ERRATum) + 1.3 packing quanta. DO NOT tighten further.
            float eps = fmaf(sqrtf(rn[g]), 4e-4f, fmaf(fabsf(a1), 4e-5f, 1e-6f));
            flg[g] = (a2 - a1) < eps;
        }

        // ---- rare: exact fp32 wave-cooperative rescan of ambiguous points ----
        unsigned long long bm0 = __ballot((l < 16) && flg[0]);
        unsigned long long bm1 = __ballot((l < 16) && flg[1]);
        #pragma unroll
        for (int g = 0; g < 2; ++g) {
            unsigned long long bm = g ? bm1 : bm0;
            while (bm) {
                int p = __ffsll(bm) - 1;
                bm &= bm - 1;
                float rp[32];
                #pragma unroll
                for (int qq = 0; qq < 4; ++qq)
                    #pragma unroll
                    for (int j = 0; j < 8; ++j)
                        rp[qq*8 + j] = __shfl(r[g][j], qq*16 + p);
                float bests = FLTMAX; int bestk = 0;
                #pragma unroll
                for (int c = 0; c < 4; ++c) {
                    int k = (c << 6) + l;
                    const float4* ck = (const float4*)(cbq + (size_t)k * DIMS);
                    float a0=0.f,a1=0.f,a2=0.f,a3=0.f;
                    #pragma unroll
                    for (int j = 0; j < 8; ++j) {
                        float4 f = ck[j];
                        a0 = fmaf(rp[4*j+0], f.x, a0);
                        a1 = fmaf(rp[4*j+1], f.y, a1);
                        a2 = fmaf(rp[4*j+2], f.z, a2);
                        a3 = fmaf(rp[4*j+3], f.w, a3);
                    }
                    float sc = fmaf(-2.f, (a0+a1)+(a2+a3), 2.f * hnq[k]);
                    bool lt = sc < bests;
                    bests = lt ? sc : bests;  bestk = lt ? k : bestk;
                }
                #pragma unroll
                for (int off = 1; off < 64; off <<= 1) {
                    float so = __shfl_xor(bests, off);
                    int   ko = __shfl_xor(bestk, off);
                    bool take = (so < bests) || (so == bests && ko < bestk);
                    bests = take ? so : bests;
                    bestk = take ? ko : bestk;
                }
                if (cl == p) bip[g] = bestk;
            }
        }

        // ---- gather chosen codes (exact fp32), update residual, loss, indices ----
        #pragma unroll
        for (int g = 0; g < 2; ++g) {
            const float4* cq = (const float4*)(cbq + (size_t)bip[g] * DIMS + qo * 8);
            float4 c0 = cq[0], c1 = cq[1];
            r[g][0]-=c0.x; r[g][1]-=c0.y; r[g][2]-=c0.z; r[g][3]-=c0.w;
            r[g][4]-=c1.x; r[g][5]-=c1.y; r[g][6]-=c1.z; r[g][7]-=c1.w;
            #pragma unroll
            for (int j = 0; j < 8; ++j) la = fmaf(r[g][j], r[g][j], la);
            if (l < 16)
                out_idx[(size_t)(base + g*16 + l) * NQ + q] = (float)bip[g];
        }
    }

    // ---- epilogue: x_q = x - r_final ----
    #pragma unroll
    for (int g = 0; g < 2; ++g) {
        size_t o = (size_t)(base + g*16 + cl) * DIMS + qo * 8;
        const float4* xp = (const float4*)(x + o);
        float4 a = xp[0], c = xp[1];
        float4* op = (float4*)(out_xq + o);
        op[0] = make_float4(a.x - r[g][0], a.y - r[g][1], a.z - r[g][2], a.w - r[g][3]);
        op[1] = make_float4(c.x - r[g][4], c.y - r[g][5], c.z - r[g][6], c.w - r[g][7]);
    }

    // ---- loss: wave -> block -> one atomicAdd ----
    float v = la;
    #pragma unroll
    for (int off = 1; off < 64; off <<= 1)
        v += __shfl_xor(v, off);
    if (l == 0) s_ws[w] = v;
    __syncthreads();
    if (t == 0) {
        const float scale = (1.0f + BETA) / ((float)NQ * 262144.0f * (float)DIMS);
        atomicAdd(out_loss, (s_ws[0] + s_ws[1] + s_ws[2] + s_ws[3]) * scale);
    }
}

extern "C" void kernel_launch(void* const* d_in, const int* in_sizes, int n_in,
                              void* d_out, int out_size, void* d_ws, size_t ws_size,
                              hipStream_t stream) {
    const float* x  = (const float*)d_in[0];   // [N, 32]
    const float* cb = (const float*)d_in[1];   // [4, 256, 32]
    float* out = (float*)d_out;

    const int N = in_sizes[0] / DIMS;          // 262144
    float* out_xq   = out;
    float* out_loss = out + (size_t)N * DIMS;
    float* out_idx  = out + (size_t)N * DIMS + 1;

    // workspace layout: hi [4*1024*16B] | lo [4*1024*16B] | hn [4*256*4B] = 132 KB
    short* ws_hi = (short*)d_ws;
    short* ws_lo = (short*)((char*)d_ws + 65536);
    float* ws_hn = (float*)((char*)d_ws + 131072);

    rvq_prep<<<dim3(NQ), dim3(KC), 0, stream>>>(cb, ws_hi, ws_lo, ws_hn, out_loss);
    rvq_kernel<<<dim3(N / 128), dim3(256), 0, stream>>>(x, cb, ws_hi, ws_lo, ws_hn,
                                                        out_xq, out_loss, out_idx);
}